// Round 3
// baseline (586.411 us; speedup 1.0000x reference)
//
#include <hip/hip_runtime.h>
#include <math.h>

// N=16384, D=4096, E=256, TOPK=6, scale=1.5
constexpr int D     = 4096;
constexpr int D2    = 2048;     // float2 per row
constexpr int D4    = 1024;     // float4 per row
constexpr int E     = 256;
constexpr int TK    = 6;
constexpr int BM    = 64;       // rows per block
constexpr int NT    = 1024;     // 16 waves = 4 waves/SIMD
constexpr int NTILE = 128;      // D / 32
constexpr float TAU = 3e-5f;    // ambiguity threshold

typedef __attribute__((ext_vector_type(8)))  short short8;
typedef __attribute__((ext_vector_type(16))) float float16;
typedef unsigned short ushort_t;

#define GAS __attribute__((address_space(1)))
#define LAS __attribute__((address_space(3)))

__device__ __forceinline__ ushort_t f2bf(float f) {  // RTNE fp32->bf16
  unsigned u = __float_as_uint(f);
  return (ushort_t)((u + 0x7fffu + ((u >> 16) & 1u)) >> 16);
}
__device__ __forceinline__ float bf2f(ushort_t h) {
  return __uint_as_float(((unsigned)h) << 16);
}
__device__ __forceinline__ int swz4(int r) { return (r & 3) ^ ((r >> 2) & 3); }

__device__ __forceinline__ void gload_lds16(const ushort_t* g, ushort_t* l) {
  __builtin_amdgcn_global_load_lds((const GAS unsigned int*)g,
                                   (LAS unsigned int*)l, 16, 0, 0);
}

// 16 waves: wave (eg, kh) = all 64 rows x experts [32eg,32eg+32), k-half kh.
// B staged per (eg,kh): kh=0 wave stages hi plane, kh=1 stages lo plane;
// both consume both -> counted vmcnt BEFORE the tile barrier publishes it.
struct __align__(16) SMem {
  union {
    struct {                        // 144 KB staging
      ushort_t Bh[4][8][32 * 32];   // [buf][eg][expert*32+k]
      ushort_t Bl[4][8][32 * 32];
      ushort_t Ah[2][BM * 32];
      ushort_t Al[2][BM * 32];
    } st;
    struct {                        // epilogue (staging dead)
      float red[8][2][16][64];      // kh-pair accumulator reduction, 64 KB
      float val[BM * 65];
      int   id [BM * 65];
    } ep;
  } u;
  float  bias[E];
  int    nflag;
  int    flagrow[BM];
  int    flagid[BM][8];
  double exact[8];
};
static_assert(sizeof(SMem) <= 160 * 1024, "LDS overflow");

// ---------- prepass: W fp32 -> bf16 hi/lo in workspace ----------
__global__ __launch_bounds__(256)
void conv_w(const float* __restrict__ wg, ushort_t* __restrict__ whi,
            ushort_t* __restrict__ wlo)
{
  size_t i = (size_t)blockIdx.x * 256 + threadIdx.x;   // over E*D/4
  float4 v = ((const float4*)wg)[i];
  float a[4] = {v.x, v.y, v.z, v.w};
  ushort_t h[4], l[4];
#pragma unroll
  for (int j = 0; j < 4; ++j) {
    h[j] = f2bf(a[j]);
    l[j] = f2bf(a[j] - bf2f(h[j]));
  }
  *(uint2*)&whi[i * 4] = *(uint2*)h;
  *(uint2*)&wlo[i * 4] = *(uint2*)l;
}

#define WAITV3   asm volatile("s_waitcnt vmcnt(3)" ::: "memory")
#define WAITV2   asm volatile("s_waitcnt vmcnt(2)" ::: "memory")
#define WAITV0   asm volatile("s_waitcnt vmcnt(0)" ::: "memory")
#define LGKM0    asm volatile("s_waitcnt lgkmcnt(0)" ::: "memory")
#define MEMFENCE asm volatile("" ::: "memory")

// ---------- main fused kernel ----------
__global__ __launch_bounds__(NT, 4)
void gate_kernel(const float* __restrict__ xg, const float* __restrict__ wg,
                 const float* __restrict__ bg,
                 const ushort_t* __restrict__ whi, const ushort_t* __restrict__ wlo,
                 float* __restrict__ outw, float* __restrict__ outi)
{
  __shared__ SMem sm;
  const int t    = threadIdx.x;
  const int row0 = blockIdx.x * BM;
  const int wv   = t >> 6;       // 0..15
  const int lane = t & 63;
  const int m    = lane & 31;
  const int hf   = lane >> 5;
  const int eg   = wv >> 1;      // 0..7 expert group (32 experts)
  const int kh   = wv & 1;       // k-half of each 32-k tile

  if (t < E) sm.bias[t] = bg[t];
  if (t == 0) sm.nflag = 0;

  const float2* x2 = (const float2*)xg;
  const float4* x4 = (const float4*)xg;
  const float4* w4 = (const float4*)wg;

  float16 acc0, acc1;            // rows 0-31 / 32-63 x 32 experts (k-half)
#pragma unroll
  for (int i = 0; i < 16; ++i) { acc0[i] = 0.f; acc1[i] = 0.f; }

  // A staging roles: 1 float2/thread per tile (1024 threads cover 64x32)
  const int a_row = t >> 4;      // 0..63
  const int aq    = t & 15;      // float2 column in 32-k slice

  // B staging roles: lane -> (expert-in-16-group, 16B chunk)
  const int e16 = lane >> 2;     // 0..15
  const int ch  = lane & 3;

  const int sA = swz4(m);
  const int slR = ((2 * kh + hf) ^ sA) * 8;   // fixed read slot per wave

  const ushort_t* wsrc = kh ? wlo : whi;

  auto stage_B = [&](int kt, int p) {
    ushort_t* dstbase = kh ? &sm.u.st.Bl[p][eg][0] : &sm.u.st.Bh[p][eg][0];
#pragma unroll
    for (int j = 0; j < 2; ++j) {
      const int er = j * 16 + e16;
      const int cs = ch ^ swz4(er);
      const size_t go = (size_t)(eg * 32 + er) * D + kt * 32 + cs * 8;
      gload_lds16(wsrc + go, dstbase + j * 512);
    }
  };
  auto ldx = [&](int kt) {
    return x2[(size_t)(row0 + a_row) * D2 + kt * 16 + aq];
  };
  auto store_A = [&](int p, float2 xv) {
    ushort_t h0 = f2bf(xv.x), h1 = f2bf(xv.y);
    ushort_t l0 = f2bf(xv.x - bf2f(h0)), l1 = f2bf(xv.y - bf2f(h1));
    const int c = aq >> 2, sub = aq & 3;
    const int sl = ((c ^ swz4(a_row)) << 3) + sub * 2;
    unsigned hp = (unsigned)h0 | ((unsigned)h1 << 16);
    unsigned lp = (unsigned)l0 | ((unsigned)l1 << 16);
    *(unsigned*)&sm.u.st.Ah[p][a_row * 32 + sl] = hp;
    *(unsigned*)&sm.u.st.Al[p][a_row * 32 + sl] = lp;
  };
  auto compute = [&](int pa, int pb) {
    short8 a0h = *(const short8*)&sm.u.st.Ah[pa][m * 32 + slR];
    short8 a0l = *(const short8*)&sm.u.st.Al[pa][m * 32 + slR];
    short8 a1h = *(const short8*)&sm.u.st.Ah[pa][(32 + m) * 32 + slR];
    short8 a1l = *(const short8*)&sm.u.st.Al[pa][(32 + m) * 32 + slR];
    short8 bh  = *(const short8*)&sm.u.st.Bh[pb][eg][m * 32 + slR];
    short8 bl  = *(const short8*)&sm.u.st.Bl[pb][eg][m * 32 + slR];
    acc0 = __builtin_amdgcn_mfma_f32_32x32x16_bf16(a0h, bh, acc0, 0, 0, 0);
    acc0 = __builtin_amdgcn_mfma_f32_32x32x16_bf16(a0h, bl, acc0, 0, 0, 0);
    acc0 = __builtin_amdgcn_mfma_f32_32x32x16_bf16(a0l, bh, acc0, 0, 0, 0);
    acc1 = __builtin_amdgcn_mfma_f32_32x32x16_bf16(a1h, bh, acc1, 0, 0, 0);
    acc1 = __builtin_amdgcn_mfma_f32_32x32x16_bf16(a1h, bl, acc1, 0, 0, 0);
    acc1 = __builtin_amdgcn_mfma_f32_32x32x16_bf16(a1l, bh, acc1, 0, 0, 0);
  };

  // ---- prologue ----
  stage_B(0, 0);                 // 2 VMEM
  stage_B(1, 1);                 // 2 VMEM
  float2 x0v = ldx(0);
  float2 xA  = ldx(1);
  float2 xB  = ldx(2);
  WAITV2;                        // B(0), B(1), x(0) complete
  store_A(0, x0v);
  LGKM0;
  __builtin_amdgcn_s_barrier();
  MEMFENCE;

  // ---- K loop: 3 VMEM/wave/tile; counted vmcnt BEFORE barrier so the
  // producer-drained B buffer is published to its kh-partner ----
#define TILE_BODY(KT, XS)                                                     \
  do {                                                                        \
    store_A(((KT) + 1) & 1, XS);                                              \
    { const int kl = ((KT) + 3 < NTILE) ? (KT) + 3 : NTILE - 1;               \
      XS = ldx(kl); }                                                         \
    { const int kb = ((KT) + 2 < NTILE) ? (KT) + 2 : NTILE - 1;               \
      stage_B(kb, ((KT) + 2) & 3); }                                          \
    compute((KT) & 1, (KT) & 3);                                              \
    WAITV3;                        /* B(KT+1), x(KT+2) landed */              \
    LGKM0;                         /* A writes visible */                     \
    __builtin_amdgcn_s_barrier();                                             \
    MEMFENCE;                                                                 \
  } while (0)

  for (int it = 0; it < NTILE / 4; ++it) {
    const int kt = it * 4;
    TILE_BODY(kt + 0, xA);
    TILE_BODY(kt + 1, xB);
    TILE_BODY(kt + 2, xA);
    TILE_BODY(kt + 3, xB);
  }
#undef TILE_BODY

  // drain tail garbage global_load_lds before reusing the union
  WAITV0;
  __syncthreads();

  // ---- kh-pair accumulator reduction through LDS ----
  if (kh == 1) {
#pragma unroll
    for (int r = 0; r < 16; ++r) {
      sm.u.ep.red[eg][0][r][lane] = acc0[r];
      sm.u.ep.red[eg][1][r][lane] = acc1[r];
    }
  }
  __syncthreads();
  if (kh == 0) {
#pragma unroll
    for (int r = 0; r < 16; ++r) {
      acc0[r] += sm.u.ep.red[eg][0][r][lane];
      acc1[r] += sm.u.ep.red[eg][1][r][lane];
    }
  }

  // ---- per-group top-8 over 32 experts, per row (kh==0 waves only) ----
  const int myE = eg * 32 + m;
  const float myBias = sm.bias[myE];

  if (kh == 0) {
#pragma unroll
    for (int b = 0; b < 2; ++b) {
#pragma unroll
      for (int reg = 0; reg < 16; ++reg) {
        const int row_local = b * 32 + (reg & 3) + 8 * (reg >> 2) + 4 * hf;
        float s = b ? acc1[reg] : acc0[reg];
        float v = sqrtf(fmaxf(s, 0.f) + log1pf(expf(-fabsf(s)))) + myBias;
#pragma unroll
        for (int ssel = 0; ssel < 8; ++ssel) {
          float bv = v;
#pragma unroll
          for (int off = 1; off < 32; off <<= 1)
            bv = fmaxf(bv, __shfl_xor(bv, off, 64));
          unsigned long long ball = __ballot(v == bv);
          unsigned hm = (unsigned)(ball >> (hf * 32));
          int mwin = __ffs(hm) - 1;            // lowest expert wins ties
          if (m == mwin) {
            sm.u.ep.val[row_local * 65 + eg * 8 + ssel] = v;
            sm.u.ep.id [row_local * 65 + eg * 8 + ssel] = myE;
            v = -INFINITY;
          }
        }
      }
    }
  }
  __syncthreads();

  // ---- merge 8x8 -> global top-8 per row; flag ambiguous rows ----
  if (t < 512) {
    const int r = t >> 3, g = t & 7;
    float mv[8]; int mi[8];
#pragma unroll
    for (int q = 0; q < 8; ++q) {
      mv[q] = sm.u.ep.val[r * 65 + q * 8 + g];
      mi[q] = sm.u.ep.id [r * 65 + q * 8 + g];
    }
    float tv[8]; int ti[8];
#pragma unroll
    for (int s = 0; s < 8; ++s) {
      float bv = mv[0]; int bi = mi[0];
#pragma unroll
      for (int q = 1; q < 8; ++q)
        if (mv[q] > bv || (mv[q] == bv && mi[q] < bi)) { bv = mv[q]; bi = mi[q]; }
#pragma unroll
      for (int off = 1; off < 8; off <<= 1) {
        float ov = __shfl_xor(bv, off, 64);
        int   oi = __shfl_xor(bi, off, 64);
        if (ov > bv || (ov == bv && oi < bi)) { bv = ov; bi = oi; }
      }
      tv[s] = bv; ti[s] = bi;
#pragma unroll
      for (int q = 0; q < 8; ++q)
        if (mi[q] == bi) mv[q] = -INFINITY;
    }
    if (g == 0) {
      bool flag = false;
#pragma unroll
      for (int i = 0; i < 7; ++i) flag |= (tv[i] - tv[i + 1] < TAU);
      const int grow = row0 + r;
      if (!flag) {
        float og[6], ssum = 0.f;
#pragma unroll
        for (int i = 0; i < 6; ++i) { og[i] = tv[i] - sm.bias[ti[i]]; ssum += og[i]; }
        const float sc = 1.5f / ssum;
#pragma unroll
        for (int i = 0; i < 6; ++i) {
          outw[(size_t)grow * TK + i] = og[i] * sc;
          outi[(size_t)grow * TK + i] = (float)ti[i];
        }
      } else {
        int slot = atomicAdd(&sm.nflag, 1);
        sm.flagrow[slot] = grow;
#pragma unroll
        for (int i = 0; i < 8; ++i) sm.flagid[slot][i] = ti[i];
      }
    }
  }
  __syncthreads();

  // ---- exact fp64 rescue for flagged rows (expected <1/block) ----
  const int nf = sm.nflag;
  for (int f = 0; f < nf; ++f) {
    const int grow = sm.flagrow[f];
    if (wv < 8) {
      const int e = sm.flagid[f][wv];
      double accd = 0.0;
      const float4* xr = x4 + (size_t)grow * D4 + lane * 16;
      const float4* wr = w4 + (size_t)e    * D4 + lane * 16;
#pragma unroll
      for (int i = 0; i < 16; ++i) {
        float4 xv = xr[i], wl = wr[i];
        accd = fma((double)xv.x, (double)wl.x, accd);
        accd = fma((double)xv.y, (double)wl.y, accd);
        accd = fma((double)xv.z, (double)wl.z, accd);
        accd = fma((double)xv.w, (double)wl.w, accd);
      }
#pragma unroll
      for (int off = 1; off < 64; off <<= 1)
        accd += __shfl_xor(accd, off, 64);
      if (lane == 0) {
        double sp = fmax(accd, 0.0) + log1p(exp(-fabs(accd)));
        sm.exact[wv] = sqrt(sp);   // orig (unbiased) score
      }
    }
    __syncthreads();
    if (t == 0) {
      double ov[8]; int oid[8], ordr[8];
      for (int i = 0; i < 8; ++i) { ov[i] = sm.exact[i]; oid[i] = sm.flagid[f][i]; ordr[i] = i; }
      for (int i = 0; i < 6; ++i) {
        int b = i;
        for (int j = i + 1; j < 8; ++j) {
          double bj = ov[ordr[j]] + (double)sm.bias[oid[ordr[j]]];
          double bb = ov[ordr[b]] + (double)sm.bias[oid[ordr[b]]];
          if (bj > bb || (bj == bb && oid[ordr[j]] < oid[ordr[b]])) b = j;
        }
        int tmp = ordr[i]; ordr[i] = ordr[b]; ordr[b] = tmp;
      }
      double ssum = 0.0;
      for (int i = 0; i < 6; ++i) ssum += ov[ordr[i]];
      double sc = 1.5 / ssum;
      for (int i = 0; i < 6; ++i) {
        outw[(size_t)grow * TK + i] = (float)(ov[ordr[i]] * sc);
        outi[(size_t)grow * TK + i] = (float)oid[ordr[i]];
      }
    }
    __syncthreads();
  }
}

extern "C" void kernel_launch(void* const* d_in, const int* in_sizes, int n_in,
                              void* d_out, int out_size, void* d_ws, size_t ws_size,
                              hipStream_t stream) {
  const float* x = (const float*)d_in[0];
  const float* w = (const float*)d_in[1];
  const float* b = (const float*)d_in[2];
  float* out  = (float*)d_out;
  const int N = in_sizes[0] / D;          // 16384

  ushort_t* whi = (ushort_t*)d_ws;                      // E*D bf16 = 2 MB
  ushort_t* wlo = whi + (size_t)E * D;                  // +2 MB

  float* outw = out;                      // [N,6] weights
  float* outi = out + (size_t)N * TK;     // [N,6] indices (as float)

  hipLaunchKernelGGL(conv_w, dim3(E * D / 4 / 256), dim3(256), 0, stream,
                     w, whi, wlo);
  hipLaunchKernelGGL(gate_kernel, dim3(N / BM), dim3(NT), 0, stream,
                     x, w, b, whi, wlo, outw, outi);
}

// Round 4
// 552.666 us; speedup vs baseline: 1.0611x; 1.0611x over previous
//
#include <hip/hip_runtime.h>
#include <math.h>

// N=16384, D=4096, E=256, TOPK=6, scale=1.5
constexpr int D     = 4096;
constexpr int D4    = 1024;     // float4 per row
constexpr int E     = 256;
constexpr int TK    = 6;
constexpr int BM    = 64;       // rows per block
constexpr int NT    = 1024;     // 16 waves = 4 waves/SIMD
constexpr int CK    = 512;      // k-chunk staged in LDS
constexpr int NCH   = D / CK;   // 8 chunks
constexpr int NST   = CK / 32;  // 16 subtiles per chunk
constexpr float TAU = 3e-5f;    // ambiguity threshold

typedef __attribute__((ext_vector_type(8)))  short short8;
typedef __attribute__((ext_vector_type(16))) float float16;
typedef unsigned short ushort_t;

__device__ __forceinline__ ushort_t f2bf(float f) {  // RTNE fp32->bf16
  unsigned u = __float_as_uint(f);
  return (ushort_t)((u + 0x7fffu + ((u >> 16) & 1u)) >> 16);
}
__device__ __forceinline__ float bf2f(ushort_t h) {
  return __uint_as_float(((unsigned)h) << 16);
}

// 16 waves: wave (eg, kh) = 64 rows x experts [32eg,32eg+32), k-half kh.
// K-loop is BARRIER-FREE per subtile: B read direct global->reg from the
// tile-major repacked W' (coalesced 16B/lane); A read from LDS chunk staged
// once per 512 k (2 barriers per chunk, 16 total).
struct __align__(16) SMem {
  union {
    struct {                        // 128 KB: A2[row][plane][512] bf16
      ushort_t A2[BM * 1024];       // row stride 1024 el; +512 = lo plane
    } st;
    struct {                        // epilogue (staging dead)
      float red[8][2][16][64];      // kh-pair accumulator reduction, 64 KB
      float val[BM * 65];
      int   id [BM * 65];
    } ep;
  } u;
  float  bias[E];
  int    nflag;
  int    flagrow[BM];
  int    flagid[BM][8];
  double exact[8];
};
static_assert(sizeof(SMem) <= 160 * 1024, "LDS overflow");

// ---------- prepass: W fp32 -> bf16 hi/lo, TILE-MAJOR [kt][e][32] ----------
__global__ __launch_bounds__(256)
void conv_w(const float* __restrict__ wg, ushort_t* __restrict__ whi,
            ushort_t* __restrict__ wlo)
{
  size_t i = (size_t)blockIdx.x * 256 + threadIdx.x;   // over E*D/4
  const int e  = (int)(i >> 10);          // i*4 / D
  const int k4 = (int)(i & 1023);
  const int kt = k4 >> 3;                 // k/32
  const int kw = (k4 & 7) * 4;            // k%32
  float4 v = ((const float4*)wg)[i];
  float a[4] = {v.x, v.y, v.z, v.w};
  ushort_t h[4], l[4];
#pragma unroll
  for (int j = 0; j < 4; ++j) {
    h[j] = f2bf(a[j]);
    l[j] = f2bf(a[j] - bf2f(h[j]));
  }
  const size_t dst = (size_t)kt * (E * 32) + e * 32 + kw;
  *(uint2*)&whi[dst] = *(uint2*)h;
  *(uint2*)&wlo[dst] = *(uint2*)l;
}

// ---------- main fused kernel ----------
__global__ __launch_bounds__(NT, 4)
void gate_kernel(const float* __restrict__ xg, const float* __restrict__ wg,
                 const float* __restrict__ bg,
                 const ushort_t* __restrict__ whi, const ushort_t* __restrict__ wlo,
                 float* __restrict__ outw, float* __restrict__ outi)
{
  __shared__ SMem sm;
  const int t    = threadIdx.x;
  const int row0 = blockIdx.x * BM;
  const int wv   = t >> 6;       // 0..15
  const int lane = t & 63;
  const int m    = lane & 31;
  const int hf   = lane >> 5;
  const int eg   = wv >> 1;      // 0..7 expert group (32 experts)
  const int kh   = wv & 1;       // k-half of each 32-k tile

  if (t < E) sm.bias[t] = bg[t];
  if (t == 0) sm.nflag = 0;

  const float4* x4 = (const float4*)xg;
  const float4* w4 = (const float4*)wg;

  float16 acc0, acc1;            // rows 0-31 / 32-63 x 32 experts (k-half)
#pragma unroll
  for (int i = 0; i < 16; ++i) { acc0[i] = 0.f; acc1[i] = 0.f; }

  // A staging roles: row = t>>4, float4-column kc = t&15 (8 f4 per thread)
  const int a_row = t >> 4;
  const int kc    = t & 15;

  // A fragment read bases (swizzled): elem = r*1024 + plane*512
  //                                        + ((s*4+q)^(r&7))*8
  // decomposed: (q^(m&3))*8 + ((s^b2))*32, b2 = (m>>2)&1
  const int q  = kh * 2 + hf;
  const int b2 = (m >> 2) & 1;
  const ushort_t* a0P = &sm.u.st.A2[m        * 1024 + ((q ^ (m & 3)) << 3)];
  const ushort_t* a1P = &sm.u.st.A2[(32 + m) * 1024 + ((q ^ (m & 3)) << 3)];

  // B direct-load base (tile-major W'): elem = kt*8192 + e*32 + kh*16 + hf*8
  const size_t bOff = (size_t)(eg * 32 + m) * 32 + kh * 16 + hf * 8;

  auto stage_A = [&](int c) {
    const float4* src = x4 + (size_t)(row0 + a_row) * D4 + c * 128 + kc;
#pragma unroll
    for (int j = 0; j < 8; ++j) {
      float4 v = src[j * 16];
      float a[4] = {v.x, v.y, v.z, v.w};
      ushort_t h[4], l[4];
#pragma unroll
      for (int i = 0; i < 4; ++i) {
        h[i] = f2bf(a[i]);
        l[i] = f2bf(a[i] - bf2f(h[i]));
      }
      const int slot = j * 8 + (kc >> 1);
      const int half = kc & 1;
      const int sw   = ((slot ^ (a_row & 7)) << 3) + half * 4;
      *(uint2*)&sm.u.st.A2[a_row * 1024 + sw]       = *(uint2*)h;
      *(uint2*)&sm.u.st.A2[a_row * 1024 + 512 + sw] = *(uint2*)l;
    }
  };

  // ---- K loop: 8 chunks x 16 barrier-free subtiles ----
  for (int c = 0; c < NCH; ++c) {
    __syncthreads();                       // prev chunk's A reads complete
    stage_A(c);
    __syncthreads();                       // A chunk published

    const ushort_t* bH = whi + (size_t)(c * NST) * 8192 + bOff;
    const ushort_t* bL = wlo + (size_t)(c * NST) * 8192 + bOff;
#pragma unroll 4
    for (int s = 0; s < NST; ++s) {
      short8 bh = *(const short8*)(bH + (size_t)s * 8192);
      short8 bl = *(const short8*)(bL + (size_t)s * 8192);
      const int ao = (s ^ b2) << 5;
      short8 a0h = *(const short8*)(a0P + ao);
      short8 a0l = *(const short8*)(a0P + 512 + ao);
      short8 a1h = *(const short8*)(a1P + ao);
      short8 a1l = *(const short8*)(a1P + 512 + ao);
      acc0 = __builtin_amdgcn_mfma_f32_32x32x16_bf16(a0h, bh, acc0, 0, 0, 0);
      acc0 = __builtin_amdgcn_mfma_f32_32x32x16_bf16(a0h, bl, acc0, 0, 0, 0);
      acc0 = __builtin_amdgcn_mfma_f32_32x32x16_bf16(a0l, bh, acc0, 0, 0, 0);
      acc1 = __builtin_amdgcn_mfma_f32_32x32x16_bf16(a1h, bh, acc1, 0, 0, 0);
      acc1 = __builtin_amdgcn_mfma_f32_32x32x16_bf16(a1h, bl, acc1, 0, 0, 0);
      acc1 = __builtin_amdgcn_mfma_f32_32x32x16_bf16(a1l, bh, acc1, 0, 0, 0);
    }
  }

  __syncthreads();                         // A2 dead; union reuse safe

  // ---- kh-pair accumulator reduction through LDS ----
  if (kh == 1) {
#pragma unroll
    for (int r = 0; r < 16; ++r) {
      sm.u.ep.red[eg][0][r][lane] = acc0[r];
      sm.u.ep.red[eg][1][r][lane] = acc1[r];
    }
  }
  __syncthreads();
  if (kh == 0) {
#pragma unroll
    for (int r = 0; r < 16; ++r) {
      acc0[r] += sm.u.ep.red[eg][0][r][lane];
      acc1[r] += sm.u.ep.red[eg][1][r][lane];
    }
  }

  // ---- per-group top-8 over 32 experts, per row (kh==0 waves only) ----
  const int myE = eg * 32 + m;
  const float myBias = sm.bias[myE];

  if (kh == 0) {
#pragma unroll
    for (int b = 0; b < 2; ++b) {
#pragma unroll
      for (int reg = 0; reg < 16; ++reg) {
        const int row_local = b * 32 + (reg & 3) + 8 * (reg >> 2) + 4 * hf;
        float s = b ? acc1[reg] : acc0[reg];
        float v = sqrtf(fmaxf(s, 0.f) + log1pf(expf(-fabsf(s)))) + myBias;
#pragma unroll
        for (int ssel = 0; ssel < 8; ++ssel) {
          float bv = v;
#pragma unroll
          for (int off = 1; off < 32; off <<= 1)
            bv = fmaxf(bv, __shfl_xor(bv, off, 64));
          unsigned long long ball = __ballot(v == bv);
          unsigned hm = (unsigned)(ball >> (hf * 32));
          int mwin = __ffs(hm) - 1;            // lowest expert wins ties
          if (m == mwin) {
            sm.u.ep.val[row_local * 65 + eg * 8 + ssel] = v;
            sm.u.ep.id [row_local * 65 + eg * 8 + ssel] = myE;
            v = -INFINITY;
          }
        }
      }
    }
  }
  __syncthreads();

  // ---- merge 8x8 -> global top-8 per row; flag ambiguous rows ----
  if (t < 512) {
    const int r = t >> 3, g = t & 7;
    float mv[8]; int mi[8];
#pragma unroll
    for (int q2 = 0; q2 < 8; ++q2) {
      mv[q2] = sm.u.ep.val[r * 65 + q2 * 8 + g];
      mi[q2] = sm.u.ep.id [r * 65 + q2 * 8 + g];
    }
    float tv[8]; int ti[8];
#pragma unroll
    for (int s = 0; s < 8; ++s) {
      float bv = mv[0]; int bi = mi[0];
#pragma unroll
      for (int q2 = 1; q2 < 8; ++q2)
        if (mv[q2] > bv || (mv[q2] == bv && mi[q2] < bi)) { bv = mv[q2]; bi = mi[q2]; }
#pragma unroll
      for (int off = 1; off < 8; off <<= 1) {
        float ov = __shfl_xor(bv, off, 64);
        int   oi = __shfl_xor(bi, off, 64);
        if (ov > bv || (ov == bv && oi < bi)) { bv = ov; bi = oi; }
      }
      tv[s] = bv; ti[s] = bi;
#pragma unroll
      for (int q2 = 0; q2 < 8; ++q2)
        if (mi[q2] == bi) mv[q2] = -INFINITY;
    }
    if (g == 0) {
      bool flag = false;
#pragma unroll
      for (int i = 0; i < 7; ++i) flag |= (tv[i] - tv[i + 1] < TAU);
      const int grow = row0 + r;
      if (!flag) {
        float og[6], ssum = 0.f;
#pragma unroll
        for (int i = 0; i < 6; ++i) { og[i] = tv[i] - sm.bias[ti[i]]; ssum += og[i]; }
        const float sc = 1.5f / ssum;
#pragma unroll
        for (int i = 0; i < 6; ++i) {
          outw[(size_t)grow * TK + i] = og[i] * sc;
          outi[(size_t)grow * TK + i] = (float)ti[i];
        }
      } else {
        int slot = atomicAdd(&sm.nflag, 1);
        sm.flagrow[slot] = grow;
#pragma unroll
        for (int i = 0; i < 8; ++i) sm.flagid[slot][i] = ti[i];
      }
    }
  }
  __syncthreads();

  // ---- exact fp64 rescue for flagged rows (expected <1/block) ----
  const int nf = sm.nflag;
  for (int f = 0; f < nf; ++f) {
    const int grow = sm.flagrow[f];
    if (wv < 8) {
      const int e = sm.flagid[f][wv];
      double accd = 0.0;
      const float4* xr = x4 + (size_t)grow * D4 + lane * 16;
      const float4* wr = w4 + (size_t)e    * D4 + lane * 16;
#pragma unroll
      for (int i = 0; i < 16; ++i) {
        float4 xv = xr[i], wl = wr[i];
        accd = fma((double)xv.x, (double)wl.x, accd);
        accd = fma((double)xv.y, (double)wl.y, accd);
        accd = fma((double)xv.z, (double)wl.z, accd);
        accd = fma((double)xv.w, (double)wl.w, accd);
      }
#pragma unroll
      for (int off = 1; off < 64; off <<= 1)
        accd += __shfl_xor(accd, off, 64);
      if (lane == 0) {
        double sp = fmax(accd, 0.0) + log1p(exp(-fabs(accd)));
        sm.exact[wv] = sqrt(sp);   // orig (unbiased) score
      }
    }
    __syncthreads();
    if (t == 0) {
      double ov[8]; int oid[8], ordr[8];
      for (int i = 0; i < 8; ++i) { ov[i] = sm.exact[i]; oid[i] = sm.flagid[f][i]; ordr[i] = i; }
      for (int i = 0; i < 6; ++i) {
        int b = i;
        for (int j = i + 1; j < 8; ++j) {
          double bj = ov[ordr[j]] + (double)sm.bias[oid[ordr[j]]];
          double bb = ov[ordr[b]] + (double)sm.bias[oid[ordr[b]]];
          if (bj > bb || (bj == bb && oid[ordr[j]] < oid[ordr[b]])) b = j;
        }
        int tmp = ordr[i]; ordr[i] = ordr[b]; ordr[b] = tmp;
      }
      double ssum = 0.0;
      for (int i = 0; i < 6; ++i) ssum += ov[ordr[i]];
      double sc = 1.5 / ssum;
      for (int i = 0; i < 6; ++i) {
        outw[(size_t)grow * TK + i] = (float)(ov[ordr[i]] * sc);
        outi[(size_t)grow * TK + i] = (float)oid[ordr[i]];
      }
    }
    __syncthreads();
  }
}

extern "C" void kernel_launch(void* const* d_in, const int* in_sizes, int n_in,
                              void* d_out, int out_size, void* d_ws, size_t ws_size,
                              hipStream_t stream) {
  const float* x = (const float*)d_in[0];
  const float* w = (const float*)d_in[1];
  const float* b = (const float*)d_in[2];
  float* out  = (float*)d_out;
  const int N = in_sizes[0] / D;          // 16384

  ushort_t* whi = (ushort_t*)d_ws;                      // E*D bf16 = 2 MB (tile-major)
  ushort_t* wlo = whi + (size_t)E * D;                  // +2 MB

  float* outw = out;                      // [N,6] weights
  float* outi = out + (size_t)N * TK;     // [N,6] indices (as float)

  hipLaunchKernelGGL(conv_w, dim3(E * D / 4 / 256), dim3(256), 0, stream,
                     w, whi, wlo);
  hipLaunchKernelGGL(gate_kernel, dim3(N / BM), dim3(NT), 0, stream,
                     x, w, b, whi, wlo, outw, outi);
}